// Round 2
// baseline (347.714 us; speedup 1.0000x reference)
//
#include <hip/hip_runtime.h>

// SwappedPredictionLoss: Sinkhorn-Knopp (3 iters) + swapped cross-entropy.
//
// Math: q[b,k] = exp(S[b,k]/eps) * u_b * v_k  (diagonal-scaling form).
//   row-normalize (over b):  v_k = 1 / (K * R_k),  R_k = sum_b e_bk * u_b
//   col-normalize (over k):  u_b = 1 / (B * C_b),  C_b = sum_k e_bk * v_k
// The initial global sum normalization cancels. Final loss per pair (s,t):
//   loss = (1/B) sum_b lse_t[b]  -  sum_b u_b * sum_k e_bk * v_k * S_t[b,k]/T
// using sum_k qhat = 1 exactly (last op is a col-normalize in the reference).
//
// NOTE: harness passes integer inputs as int32 (NOT int64, despite reference
// declaring jnp.int64) — reading as long long was the R1 correctness bug.

#define NVIEWS 2
#define BATCH 4096
#define KPROTO 3000
#define KPAD 3072
#define NTHREADS 256
#define COLSUM_CHUNKS 32
#define ROWS_PER_BLOCK (BATCH / COLSUM_CHUNKS)  // 128

constexpr float EPS_INV = 20.0f;   // 1/0.05
constexpr float TEMP_INV = 10.0f;  // 1/0.1
constexpr float KF = 3000.0f;
constexpr float BF = 4096.0f;

__device__ __forceinline__ float fast_rcp(float x) { return __builtin_amdgcn_rcpf(x); }

__device__ __forceinline__ float wave_reduce_sum(float x) {
#pragma unroll
  for (int off = 32; off > 0; off >>= 1) x += __shfl_down(x, off, 64);
  return x;
}

// R_out[v][k] += sum over a 128-row chunk of exp(S*EPS_INV) * u_b,
// where u_b = 1/(C_in[v][b]*B), or u_b = 1 when C_in == nullptr.
__global__ void colsum_kernel(const float* __restrict__ S, const float* __restrict__ Cin,
                              float* __restrict__ Rout) {
  const int v = blockIdx.z;
  const int k = blockIdx.x * NTHREADS + threadIdx.x;
  if (k >= KPROTO) return;
  const int b0 = blockIdx.y * ROWS_PER_BLOCK;
  const float* Sv = S + (size_t)v * BATCH * KPROTO;
  float acc = 0.0f;
  if (Cin != nullptr) {
    const float* Cv = Cin + v * BATCH;
#pragma unroll 4
    for (int b = b0; b < b0 + ROWS_PER_BLOCK; ++b) {
      float u = fast_rcp(Cv[b] * BF);
      acc += __expf(Sv[(size_t)b * KPROTO + k] * EPS_INV) * u;
    }
  } else {
#pragma unroll 4
    for (int b = b0; b < b0 + ROWS_PER_BLOCK; ++b) {
      acc += __expf(Sv[(size_t)b * KPROTO + k] * EPS_INV);
    }
  }
  atomicAdd(&Rout[v * KPAD + k], acc);
}

// C_out[v][b] = sum_k exp(S*EPS_INV) / (R_in[v][k] * K)
__global__ void rowsum_kernel(const float* __restrict__ S, const float* __restrict__ Rin,
                              float* __restrict__ Cout) {
  const int v = blockIdx.z;
  const int b = blockIdx.x;
  const float4* row4 = (const float4*)(S + ((size_t)v * BATCH + b) * KPROTO);
  const float4* R4 = (const float4*)(Rin + v * KPAD);
  float acc = 0.0f;
  for (int j = threadIdx.x; j < KPROTO / 4; j += NTHREADS) {
    float4 sv = row4[j];
    float4 rv = R4[j];
    acc += __expf(sv.x * EPS_INV) * fast_rcp(rv.x * KF);
    acc += __expf(sv.y * EPS_INV) * fast_rcp(rv.y * KF);
    acc += __expf(sv.z * EPS_INV) * fast_rcp(rv.z * KF);
    acc += __expf(sv.w * EPS_INV) * fast_rcp(rv.w * KF);
  }
  acc = wave_reduce_sum(acc);
  __shared__ float sm[NTHREADS / 64];
  const int lane = threadIdx.x & 63;
  const int w = threadIdx.x >> 6;
  if (lane == 0) sm[w] = acc;
  __syncthreads();
  if (threadIdx.x == 0) {
    Cout[v * BATCH + b] = sm[0] + sm[1] + sm[2] + sm[3];
  }
}

// Per pair p: s = code_ids[p], t = score_ids[p].
// Per row b: lse = log(sum_k exp(S_t/T));  cross = sum_k e_s * v_k * (S_t/T)
// atomicAdd(out, lse/B - cross * u_b)
__global__ void loss_kernel(const float* __restrict__ S,
                            const int* __restrict__ code_ids,
                            const int* __restrict__ score_ids,
                            const float* __restrict__ R3, const float* __restrict__ C3,
                            float* __restrict__ out) {
  const int p = blockIdx.z;
  const int s = min(max(code_ids[p], 0), NVIEWS - 1);
  const int t = min(max(score_ids[p], 0), NVIEWS - 1);
  const int b = blockIdx.x;
  const float4* rowS4 = (const float4*)(S + ((size_t)s * BATCH + b) * KPROTO);
  const float4* rowT4 = (const float4*)(S + ((size_t)t * BATCH + b) * KPROTO);
  const float4* R4 = (const float4*)(R3 + s * KPAD);
  float se = 0.0f, cr = 0.0f;
  for (int j = threadIdx.x; j < KPROTO / 4; j += NTHREADS) {
    float4 sv = rowS4[j];
    float4 tv = rowT4[j];
    float4 rv = R4[j];
    float st;
    st = tv.x * TEMP_INV; se += __expf(st); cr += __expf(sv.x * EPS_INV) * fast_rcp(rv.x * KF) * st;
    st = tv.y * TEMP_INV; se += __expf(st); cr += __expf(sv.y * EPS_INV) * fast_rcp(rv.y * KF) * st;
    st = tv.z * TEMP_INV; se += __expf(st); cr += __expf(sv.z * EPS_INV) * fast_rcp(rv.z * KF) * st;
    st = tv.w * TEMP_INV; se += __expf(st); cr += __expf(sv.w * EPS_INV) * fast_rcp(rv.w * KF) * st;
  }
  se = wave_reduce_sum(se);
  cr = wave_reduce_sum(cr);
  __shared__ float sm[8];
  const int lane = threadIdx.x & 63;
  const int w = threadIdx.x >> 6;
  if (lane == 0) { sm[w] = se; sm[4 + w] = cr; }
  __syncthreads();
  if (threadIdx.x == 0) {
    float lse = __logf(sm[0] + sm[1] + sm[2] + sm[3]);
    float crT = sm[4] + sm[5] + sm[6] + sm[7];
    float u = fast_rcp(C3[s * BATCH + b] * BF);
    atomicAdd(out, lse * (1.0f / BF) - crT * u);
  }
}

extern "C" void kernel_launch(void* const* d_in, const int* in_sizes, int n_in,
                              void* d_out, int out_size, void* d_ws, size_t ws_size,
                              hipStream_t stream) {
  const float* S = (const float*)d_in[0];
  const int* code_ids = (const int*)d_in[1];   // harness ships integers as int32
  const int* score_ids = (const int*)d_in[2];

  float* ws = (float*)d_ws;
  // ws layout (floats): R1,R2,R3 [NVIEWS][KPAD] then C1,C2,C3 [NVIEWS][BATCH]
  float* R1 = ws;
  float* R2 = R1 + NVIEWS * KPAD;
  float* R3 = R2 + NVIEWS * KPAD;
  float* C1 = R3 + NVIEWS * KPAD;
  float* C2 = C1 + NVIEWS * BATCH;
  float* C3 = C2 + NVIEWS * BATCH;

  // zero atomic accumulators (R buffers) and the output scalar
  hipMemsetAsync(ws, 0, sizeof(float) * 3 * NVIEWS * KPAD, stream);
  hipMemsetAsync(d_out, 0, sizeof(float) * out_size, stream);

  dim3 blk(NTHREADS);
  dim3 csGrid(KPAD / NTHREADS, COLSUM_CHUNKS, NVIEWS);  // 12 x 32 x 2
  dim3 rsGrid(BATCH, 1, NVIEWS);

  colsum_kernel<<<csGrid, blk, 0, stream>>>(S, nullptr, R1);   // R1_k = sum_b e
  rowsum_kernel<<<rsGrid, blk, 0, stream>>>(S, R1, C1);        // C1_b = sum_k e/(R1*K)
  colsum_kernel<<<csGrid, blk, 0, stream>>>(S, C1, R2);        // R2_k = sum_b e/(C1*B)
  rowsum_kernel<<<rsGrid, blk, 0, stream>>>(S, R2, C2);
  colsum_kernel<<<csGrid, blk, 0, stream>>>(S, C2, R3);
  rowsum_kernel<<<rsGrid, blk, 0, stream>>>(S, R3, C3);
  loss_kernel<<<rsGrid, blk, 0, stream>>>(S, code_ids, score_ids, R3, C3, (float*)d_out);
}

// Round 3
// 281.974 us; speedup vs baseline: 1.2331x; 1.2331x over previous
//
#include <hip/hip_runtime.h>

// SwappedPredictionLoss: Sinkhorn-Knopp (3 iters) + swapped cross-entropy.
//
// q[b,k] = B * e_bk * u_b * v_k,  e = exp(S/eps)
//   row-normalize: v_k = 1/(K*R_k),  R_k = sum_b e_bk * u_b
//   col-normalize: u_b = 1/(B*C_b),  C_b = sum_k e_bk * v_k
// loss = sum_pairs [ (1/B) sum_b lse_t[b] - sum_b u_b * sum_k e_s*v_k*(S_t/T) ]
// C3 (final col sums) is computed INLINE in the loss kernel (the cross term
// already forms e_s*v_k per element) — saves one full pass over S.
//
// R2 lesson: 8192 same-address atomicAdds serialized at ~14ns each = 113us.
// Loss now writes per-block partials to ws; final_kernel reduces them.
// Harness note: integer inputs arrive as int32 (not int64).

#define NVIEWS 2
#define BATCH 4096
#define KPROTO 3000
#define K4 750            // float4s per row (3000/4), row stride 12000B is 16B-aligned
#define KPAD 3072
#define NT 256
#define CS_ROWS 32        // rows per colsum block
#define LOSS_BLOCKS 1024  // per pair: 4096 rows / 4 rows-per-block

constexpr float EPS_INV = 20.0f;   // 1/0.05
constexpr float TEMP_INV = 10.0f;  // 1/0.1
constexpr float KF = 3000.0f;
constexpr float BF = 4096.0f;

__device__ __forceinline__ float fast_rcp(float x) { return __builtin_amdgcn_rcpf(x); }

__device__ __forceinline__ float wave_sum(float x) {
#pragma unroll
  for (int o = 32; o > 0; o >>= 1) x += __shfl_down(x, o, 64);
  return x;
}

// R_out[v][k] += sum over a CS_ROWS-row chunk of e_bk * u_b.
// u_b = 1/(C_in[v][b]*B), or 1 when Cin == nullptr.
// Thread owns one float4 of columns -> 16B/lane coalesced loads.
__global__ void colsum_kernel(const float* __restrict__ S, const float* __restrict__ Cin,
                              float* __restrict__ Rout) {
  const int v = blockIdx.z;
  const int f = blockIdx.x * NT + threadIdx.x;  // float4 index within row
  if (f >= K4) return;
  const int b0 = blockIdx.y * CS_ROWS;
  const float4* S4 = (const float4*)(S + (size_t)v * BATCH * KPROTO);
  float4 acc = {0.f, 0.f, 0.f, 0.f};
  if (Cin != nullptr) {
    const float* Cv = Cin + v * BATCH;
#pragma unroll 4
    for (int b = b0; b < b0 + CS_ROWS; ++b) {
      float u = fast_rcp(Cv[b] * BF);
      float4 sv = S4[(size_t)b * K4 + f];
      acc.x += __expf(sv.x * EPS_INV) * u;
      acc.y += __expf(sv.y * EPS_INV) * u;
      acc.z += __expf(sv.z * EPS_INV) * u;
      acc.w += __expf(sv.w * EPS_INV) * u;
    }
  } else {
#pragma unroll 4
    for (int b = b0; b < b0 + CS_ROWS; ++b) {
      float4 sv = S4[(size_t)b * K4 + f];
      acc.x += __expf(sv.x * EPS_INV);
      acc.y += __expf(sv.y * EPS_INV);
      acc.z += __expf(sv.z * EPS_INV);
      acc.w += __expf(sv.w * EPS_INV);
    }
  }
  float* R = Rout + v * KPAD + f * 4;
  atomicAdd(R + 0, acc.x);
  atomicAdd(R + 1, acc.y);
  atomicAdd(R + 2, acc.z);
  atomicAdd(R + 3, acc.w);
}

// C_out[v][b] = sum_k e_bk / (R_in[v][k] * K).  One wave per row.
__global__ void rowsum_kernel(const float* __restrict__ S, const float* __restrict__ Rin,
                              float* __restrict__ Cout) {
  const int v = blockIdx.z;
  const int wave = threadIdx.x >> 6;
  const int lane = threadIdx.x & 63;
  const int b = blockIdx.x * 4 + wave;
  const float4* row = (const float4*)(S + ((size_t)v * BATCH + b) * KPROTO);
  const float4* R4 = (const float4*)(Rin + v * KPAD);
  float acc = 0.f;
#pragma unroll
  for (int j = 0; j < 12; ++j) {
    const int f = j * 64 + lane;
    if (f < K4) {
      float4 sv = row[f];
      float4 rv = R4[f];
      acc += __expf(sv.x * EPS_INV) * fast_rcp(rv.x * KF);
      acc += __expf(sv.y * EPS_INV) * fast_rcp(rv.y * KF);
      acc += __expf(sv.z * EPS_INV) * fast_rcp(rv.z * KF);
      acc += __expf(sv.w * EPS_INV) * fast_rcp(rv.w * KF);
    }
  }
  acc = wave_sum(acc);
  if (lane == 0) Cout[v * BATCH + b] = acc;
}

// Per pair p (s=code, t=score), one wave per row b:
//   c  = sum_k e_s*v_k            (this IS C3_b, computed inline)
//   se = sum_k exp(S_t/T)
//   cr = sum_k e_s*v_k*(S_t/T)
//   row contrib = log(se)/B - cr / (c*B)
// Block sums 4 wave contribs -> one partial per block in ws (no global atomic).
__global__ void loss_kernel(const float* __restrict__ S,
                            const int* __restrict__ code_ids,
                            const int* __restrict__ score_ids,
                            const float* __restrict__ R3,
                            float* __restrict__ part) {
  const int p = blockIdx.z;
  const int s = code_ids[p] & 1;
  const int t = score_ids[p] & 1;
  const int wave = threadIdx.x >> 6;
  const int lane = threadIdx.x & 63;
  const int b = blockIdx.x * 4 + wave;
  const float4* rs = (const float4*)(S + ((size_t)s * BATCH + b) * KPROTO);
  const float4* rt = (const float4*)(S + ((size_t)t * BATCH + b) * KPROTO);
  const float4* R4 = (const float4*)(R3 + s * KPAD);
  float c = 0.f, se = 0.f, cr = 0.f;
#pragma unroll
  for (int j = 0; j < 12; ++j) {
    const int f = j * 64 + lane;
    if (f < K4) {
      float4 sv = rs[f];
      float4 tv = rt[f];
      float4 rv = R4[f];
      float w, st;
      w = __expf(sv.x * EPS_INV) * fast_rcp(rv.x * KF); st = tv.x * TEMP_INV;
      c += w; se += __expf(st); cr += w * st;
      w = __expf(sv.y * EPS_INV) * fast_rcp(rv.y * KF); st = tv.y * TEMP_INV;
      c += w; se += __expf(st); cr += w * st;
      w = __expf(sv.z * EPS_INV) * fast_rcp(rv.z * KF); st = tv.z * TEMP_INV;
      c += w; se += __expf(st); cr += w * st;
      w = __expf(sv.w * EPS_INV) * fast_rcp(rv.w * KF); st = tv.w * TEMP_INV;
      c += w; se += __expf(st); cr += w * st;
    }
  }
  c = wave_sum(c);
  se = wave_sum(se);
  cr = wave_sum(cr);
  __shared__ float sm[4];
  if (lane == 0) {
    float u = fast_rcp(c * BF);
    sm[wave] = __logf(se) * (1.0f / BF) - cr * u;
  }
  __syncthreads();
  if (threadIdx.x == 0) {
    part[p * LOSS_BLOCKS + blockIdx.x] = sm[0] + sm[1] + sm[2] + sm[3];
  }
}

__global__ void final_kernel(const float* __restrict__ part, float* __restrict__ out) {
  float a = 0.f;
  for (int i = threadIdx.x; i < NVIEWS * LOSS_BLOCKS; i += NT) a += part[i];
  a = wave_sum(a);
  __shared__ float sm[4];
  const int lane = threadIdx.x & 63;
  const int w = threadIdx.x >> 6;
  if (lane == 0) sm[w] = a;
  __syncthreads();
  if (threadIdx.x == 0) out[0] = sm[0] + sm[1] + sm[2] + sm[3];
}

extern "C" void kernel_launch(void* const* d_in, const int* in_sizes, int n_in,
                              void* d_out, int out_size, void* d_ws, size_t ws_size,
                              hipStream_t stream) {
  const float* S = (const float*)d_in[0];
  const int* code_ids = (const int*)d_in[1];   // int32 on the wire
  const int* score_ids = (const int*)d_in[2];

  float* ws = (float*)d_ws;
  // ws layout (floats): R1,R2,R3 [NVIEWS][KPAD] | C1,C2 [NVIEWS][BATCH] | part [2*LOSS_BLOCKS]
  float* R1 = ws;
  float* R2 = R1 + NVIEWS * KPAD;
  float* R3 = R2 + NVIEWS * KPAD;
  float* C1 = R3 + NVIEWS * KPAD;
  float* C2 = C1 + NVIEWS * BATCH;
  float* part = C2 + NVIEWS * BATCH;

  // zero only the atomic accumulators (R buffers)
  hipMemsetAsync(ws, 0, sizeof(float) * 3 * NVIEWS * KPAD, stream);

  dim3 blk(NT);
  dim3 csGrid((K4 + NT - 1) / NT, BATCH / CS_ROWS, NVIEWS);  // 3 x 128 x 2
  dim3 rsGrid(BATCH / 4, 1, NVIEWS);                         // 1024 x 1 x 2
  dim3 lsGrid(LOSS_BLOCKS, 1, NVIEWS);                       // 1024 x 1 x 2

  colsum_kernel<<<csGrid, blk, 0, stream>>>(S, nullptr, R1);
  rowsum_kernel<<<rsGrid, blk, 0, stream>>>(S, R1, C1);
  colsum_kernel<<<csGrid, blk, 0, stream>>>(S, C1, R2);
  rowsum_kernel<<<rsGrid, blk, 0, stream>>>(S, R2, C2);
  colsum_kernel<<<csGrid, blk, 0, stream>>>(S, C2, R3);
  loss_kernel<<<lsGrid, blk, 0, stream>>>(S, code_ids, score_ids, R3, part);
  final_kernel<<<1, blk, 0, stream>>>(part, (float*)d_out);
}